// Round 6
// baseline (1542.779 us; speedup 1.0000x reference)
//
#include <hip/hip_runtime.h>
#include <hip/hip_bf16.h>

#define N_NODES 100000
#define N_EDGES 1600000
#define IN_CH 50
#define NPB 512                                   // nodes per bucket (dst >> 9)
#define NB ((N_NODES + NPB - 1) / NPB)            // 196 buckets
#define EPB 4096                                  // edges per block, binning passes
#define NBLK_A ((N_EDGES + EPB - 1) / EPB)        // 391 blocks

// ---- 1. coarse bucket histogram ----
__global__ __launch_bounds__(256) void bucket_count(const int* __restrict__ dst,
                                                    int* __restrict__ bucket_cnt) {
    __shared__ int bc[NB];
    int t = threadIdx.x;
    if (t < NB) bc[t] = 0;
    __syncthreads();
    int e0 = blockIdx.x * EPB;
    int e1 = min(e0 + EPB, N_EDGES);
    for (int i = e0 + t; i < e1; i += 256)
        atomicAdd(&bc[dst[i] >> 9], 1);
    __syncthreads();
    if (t < NB) { int v = bc[t]; if (v) atomicAdd(&bucket_cnt[t], v); }
}

// ---- 2. exclusive scan of bucket sizes ----
__global__ __launch_bounds__(256) void bucket_scan(const int* __restrict__ bucket_cnt,
                                                   int* __restrict__ bucket_base,
                                                   int* __restrict__ bucket_cursor) {
    __shared__ int s[256];
    int t = threadIdx.x;
    int v = (t < NB) ? bucket_cnt[t] : 0;
    s[t] = v;
    __syncthreads();
    for (int off = 1; off < 256; off <<= 1) {
        int tmp = (t >= off) ? s[t - off] : 0;
        __syncthreads();
        s[t] += tmp;
        __syncthreads();
    }
    if (t < NB) { int base = s[t] - v; bucket_base[t] = base; bucket_cursor[t] = base; }
}

// ---- 3. bin edges into coarse buckets as packed (dst<<32 | src) ----
__global__ __launch_bounds__(256) void bucket_bin(const int* __restrict__ src,
                                                  const int* __restrict__ dst,
                                                  int* __restrict__ bucket_cursor,
                                                  unsigned long long* __restrict__ binned) {
    __shared__ int bc[NB];
    __shared__ int boff[NB];
    int t = threadIdx.x;
    if (t < NB) bc[t] = 0;
    __syncthreads();
    int e0 = blockIdx.x * EPB;
    int e1 = min(e0 + EPB, N_EDGES);
    for (int i = e0 + t; i < e1; i += 256)
        atomicAdd(&bc[dst[i] >> 9], 1);
    __syncthreads();
    if (t < NB) {
        int v = bc[t];
        boff[t] = v ? atomicAdd(&bucket_cursor[t], v) : 0;
        bc[t] = 0;
    }
    __syncthreads();
    for (int i = e0 + t; i < e1; i += 256) {
        int d = dst[i];
        int b = d >> 9;
        int k = atomicAdd(&bc[b], 1);
        binned[boff[b] + k] =
            ((unsigned long long)(unsigned)d << 32) | (unsigned)src[i];
    }
}

// ---- 4. per-bucket fine sort ----
__global__ __launch_bounds__(256) void bucket_fine(
    const unsigned long long* __restrict__ binned,
    const int* __restrict__ bucket_base, const int* __restrict__ bucket_cnt,
    int* __restrict__ cnt, int* __restrict__ row_start, int* __restrict__ csr_src) {
    __shared__ int lcnt[NPB];
    __shared__ int lofs[NPB];
    __shared__ int sc[256];
    int t = threadIdx.x;
    int b = blockIdx.x;
    int nbase = b * NPB;
    int ebase = bucket_base[b];
    int ecnt  = bucket_cnt[b];
    lcnt[t] = 0; lcnt[t + 256] = 0;
    __syncthreads();
    for (int i = t; i < ecnt; i += 256) {
        int d = (int)(binned[ebase + i] >> 32) - nbase;
        atomicAdd(&lcnt[d], 1);
    }
    __syncthreads();
    int v0 = lcnt[2 * t], v1 = lcnt[2 * t + 1];
    int pair = v0 + v1;
    sc[t] = pair;
    __syncthreads();
    for (int off = 1; off < 256; off <<= 1) {
        int tmp = (t >= off) ? sc[t - off] : 0;
        __syncthreads();
        sc[t] += tmp;
        __syncthreads();
    }
    int excl = sc[t] - pair;
    lofs[2 * t] = excl;
    lofs[2 * t + 1] = excl + v0;
    __syncthreads();
    {
        int n0 = nbase + t;
        if (n0 < N_NODES) { cnt[n0] = lcnt[t]; row_start[n0] = ebase + lofs[t]; }
        int n1 = nbase + t + 256;
        if (n1 < N_NODES) { cnt[n1] = lcnt[t + 256]; row_start[n1] = ebase + lofs[t + 256]; }
    }
    __syncthreads();
    for (int i = t; i < ecnt; i += 256) {
        unsigned long long p = binned[ebase + i];
        int d = (int)(p >> 32) - nbase;
        int k = atomicAdd(&lofs[d], 1);
        csr_src[ebase + k] = (int)(p & 0xffffffffULL);
    }
}

// ---- 5. pad+quantize x [N,50] fp32 -> xb [N,64] bf16 ----
__global__ __launch_bounds__(256) void pad_bf16_kernel(const float* __restrict__ x,
                                                       __hip_bfloat16* __restrict__ xb) {
    int t = blockIdx.x * blockDim.x + threadIdx.x;
    int n = t >> 6, c = t & 63;
    float v = (c < IN_CH) ? x[n * IN_CH + c] : 0.0f;
    xb[t] = __float2bfloat16(v);
}

// unpack 8 bf16 from uint4, predicated fma into acc[0..8)
__device__ __forceinline__ void upadd8(float* a, uint4 v, float p) {
    a[0] = fmaf(p, __uint_as_float(v.x << 16), a[0]);
    a[1] = fmaf(p, __uint_as_float(v.x & 0xffff0000u), a[1]);
    a[2] = fmaf(p, __uint_as_float(v.y << 16), a[2]);
    a[3] = fmaf(p, __uint_as_float(v.y & 0xffff0000u), a[3]);
    a[4] = fmaf(p, __uint_as_float(v.z << 16), a[4]);
    a[5] = fmaf(p, __uint_as_float(v.z & 0xffff0000u), a[5]);
    a[6] = fmaf(p, __uint_as_float(v.w << 16), a[6]);
    a[7] = fmaf(p, __uint_as_float(v.w & 0xffff0000u), a[7]);
}

// ---- 6. gather-mean: 4 nodes per wave, chains interleaved.
// 8 lane-groups of 8 per node; each lane loads 16B (8 bf16 ch) of one edge row.
// Writes mean fp32 [node][64].
__global__ __launch_bounds__(256) void gather_mean_kernel(
    const unsigned short* __restrict__ featb, const int* __restrict__ csr_src,
    const int* __restrict__ row_start, const int* __restrict__ cnt,
    float* __restrict__ meanout) {
    int wv   = threadIdx.x >> 6;
    int lane = threadIdx.x & 63;
    int nb   = (blockIdx.x * 4 + wv) * 4;     // 4 nodes per wave; N_NODES%16==0
    int g  = lane >> 3;
    int cw = (lane & 7) * 8;

    float acc[4][8];
    int start[4], deg[4], sv[4];
    int dmax = 0;
    #pragma unroll
    for (int i = 0; i < 4; ++i) {
        start[i] = row_start[nb + i];
        deg[i]   = cnt[nb + i];
        dmax = max(dmax, deg[i]);
        #pragma unroll
        for (int c = 0; c < 8; ++c) acc[i][c] = 0.f;
    }
    // all 4 csr loads in flight first
    #pragma unroll
    for (int i = 0; i < 4; ++i)
        sv[i] = (lane < deg[i]) ? csr_src[start[i] + lane] : 0;

    // fast path: edges [0,64) of all 4 nodes, 8 feature loads in flight per round
    #pragma unroll
    for (int cb = 0; cb < 64; cb += 16) {
        if (cb >= dmax) break;                 // wave-uniform
        #pragma unroll
        for (int i = 0; i < 4; ++i) {
            int rem = deg[i] - cb;
            if (rem > 0) {                     // wave-uniform
                int s0 = __shfl(sv[i], cb + g);
                int s1 = __shfl(sv[i], cb + 8 + g);
                float p0 = (g < rem) ? 1.f : 0.f;
                float p1 = (g + 8 < rem) ? 1.f : 0.f;
                uint4 v0 = *(const uint4*)(featb + s0 * 64 + cw);
                uint4 v1 = *(const uint4*)(featb + s1 * 64 + cw);
                upadd8(acc[i], v0, p0);
                upadd8(acc[i], v1, p1);
            }
        }
    }
    // rare: degree > 64
    if (dmax > 64) {
        for (int i = 0; i < 4; ++i) {
            for (int c0 = 64; c0 < deg[i]; c0 += 64) {
                int rem = deg[i] - c0; if (rem > 64) rem = 64;
                int sx = (lane < rem) ? csr_src[start[i] + c0 + lane] : 0;
                for (int cb = 0; cb < rem; cb += 16) {
                    int s0 = __shfl(sx, cb + g);
                    int s1 = __shfl(sx, cb + 8 + g);
                    float p0 = (cb + g < rem) ? 1.f : 0.f;
                    float p1 = (cb + 8 + g < rem) ? 1.f : 0.f;
                    uint4 v0 = *(const uint4*)(featb + s0 * 64 + cw);
                    uint4 v1 = *(const uint4*)(featb + s1 * 64 + cw);
                    upadd8(acc[i], v0, p0);
                    upadd8(acc[i], v1, p1);
                }
            }
        }
    }
    // merge 8 groups, divide, store
    #pragma unroll
    for (int i = 0; i < 4; ++i) {
        #pragma unroll
        for (int c = 0; c < 8; ++c) {
            float t = acc[i][c];
            t += __shfl_xor(t, 8);
            t += __shfl_xor(t, 16);
            t += __shfl_xor(t, 32);
            acc[i][c] = t;
        }
        float inv = 1.0f / fmaxf((float)deg[i], 1.0f);
        if (lane < 8) {
            float* dp = meanout + ((nb + i) << 6) + lane * 8;
            *(float4*)dp       = make_float4(acc[i][0] * inv, acc[i][1] * inv,
                                             acc[i][2] * inv, acc[i][3] * inv);
            *(float4*)(dp + 4) = make_float4(acc[i][4] * inv, acc[i][5] * inv,
                                             acc[i][6] * inv, acc[i][7] * inv);
        }
    }
}

// ---- 7. layer-1 GEMM: h1 = relu([x | meanX] @ W1 + b1); 16 nodes/wave, j=lane ----
__global__ __launch_bounds__(256) void gemm1_kernel(
    const float* __restrict__ x, const float* __restrict__ meanX,
    const float* __restrict__ W1, const float* __restrict__ b1,
    float* __restrict__ h1, unsigned short* __restrict__ h1b) {
    int wv   = __builtin_amdgcn_readfirstlane((int)(threadIdx.x >> 6));
    int lane = threadIdx.x & 63;
    int nb   = (blockIdx.x * 4 + wv) * 16;
    float acc[16];
    float bb = b1[lane];
    int nn[16];
    #pragma unroll
    for (int n = 0; n < 16; ++n) { acc[n] = bb; nn[n] = min(nb + n, N_NODES - 1); }
    #pragma unroll
    for (int k = 0; k < IN_CH; ++k) {
        float w = W1[k * 64 + lane];
        #pragma unroll
        for (int n = 0; n < 16; ++n)
            acc[n] = fmaf(x[nn[n] * IN_CH + k], w, acc[n]);   // uniform addr -> s_load
    }
    #pragma unroll
    for (int k = 0; k < IN_CH; ++k) {
        float w = W1[(IN_CH + k) * 64 + lane];
        #pragma unroll
        for (int n = 0; n < 16; ++n)
            acc[n] = fmaf(meanX[(nn[n] << 6) + k], w, acc[n]);
    }
    #pragma unroll
    for (int n = 0; n < 16; ++n) {
        if (nb + n < N_NODES) {
            float r = fmaxf(acc[n], 0.f);
            h1[((nb + n) << 6) + lane] = r;
            __hip_bfloat16 hb = __float2bfloat16(r);
            h1b[((nb + n) << 6) + lane] = *(unsigned short*)&hb;
        }
    }
}

// ---- 8. layers 2+3 GEMM: out = relu([h1 | meanH] @ W2 + b2) @ W3 + b3
// j = lane&31; two 32-lane halves handle two independent 16-node sets.
__global__ __launch_bounds__(256) void gemm23_kernel(
    const float* __restrict__ h1, const float* __restrict__ meanH,
    const float* __restrict__ W2, const float* __restrict__ b2,
    const float* __restrict__ W3, const float* __restrict__ b3,
    float* __restrict__ out) {
    int wv  = __builtin_amdgcn_readfirstlane((int)(threadIdx.x >> 6));
    int tid = threadIdx.x & 63;
    int j = tid & 31;
    int h = tid >> 5;
    int nb = (blockIdx.x * 4 + wv) * 32 + h * 16;
    float acc[16];
    float bb = b2[j];
    int nn[16];
    #pragma unroll
    for (int n = 0; n < 16; ++n) { acc[n] = bb; nn[n] = min(nb + n, N_NODES - 1); }
    #pragma unroll
    for (int k = 0; k < 64; ++k) {
        float w = W2[k * 32 + j];
        #pragma unroll
        for (int n = 0; n < 16; ++n)
            acc[n] = fmaf(h1[(nn[n] << 6) + k], w, acc[n]);
    }
    #pragma unroll
    for (int k = 0; k < 64; ++k) {
        float w = W2[(64 + k) * 32 + j];
        #pragma unroll
        for (int n = 0; n < 16; ++n)
            acc[n] = fmaf(meanH[(nn[n] << 6) + k], w, acc[n]);
    }
    float w3 = W3[j];
    float c3 = b3[0];
    #pragma unroll
    for (int n = 0; n < 16; ++n) {
        float v = fmaxf(acc[n], 0.f) * w3;
        v += __shfl_xor(v, 1);  v += __shfl_xor(v, 2);  v += __shfl_xor(v, 4);
        v += __shfl_xor(v, 8);  v += __shfl_xor(v, 16);
        if (j == 0 && nb + n < N_NODES) out[nb + n] = v + c3;
    }
}

extern "C" void kernel_launch(void* const* d_in, const int* in_sizes, int n_in,
                              void* d_out, int out_size, void* d_ws, size_t ws_size,
                              hipStream_t stream) {
    const float* x   = (const float*)d_in[0];
    const int*   ei  = (const int*)d_in[1];
    const int*   src = ei;
    const int*   dst = ei + N_EDGES;
    const float* W1  = (const float*)d_in[2];
    const float* b1  = (const float*)d_in[3];
    const float* W2  = (const float*)d_in[4];
    const float* b2  = (const float*)d_in[5];
    const float* W3  = (const float*)d_in[6];
    const float* b3  = (const float*)d_in[7];
    float* out = (float*)d_out;

    // ws (~71 MB): buckets | cnt | row_start | csr_src |
    //   R1 12.8MB: binned u64[E] -> xb bf16[N*64] -> h1b bf16[N*64] (sequential lifetimes)
    //   R2 25.6MB: meanX f32[N*64] -> meanH f32[N*64] (sequential lifetimes)
    //   h1 f32[N*64] 25.6MB
    char* ws = (char*)d_ws;
    auto align = [](size_t v) { return (v + 255) & ~(size_t)255; };
    size_t o = 0;
    int* bucket_cnt    = (int*)(ws + o); o = align(o + 256 * 4);
    int* bucket_base   = (int*)(ws + o); o = align(o + 256 * 4);
    int* bucket_cursor = (int*)(ws + o); o = align(o + 256 * 4);
    int* cnt       = (int*)(ws + o); o = align(o + (size_t)N_NODES * 4);
    int* row_start = (int*)(ws + o); o = align(o + (size_t)N_NODES * 4);
    int* csr_src   = (int*)(ws + o); o = align(o + (size_t)N_EDGES * 4);
    unsigned long long* binned = (unsigned long long*)(ws + o);   // 12.8 MB region R1
    __hip_bfloat16* xb  = (__hip_bfloat16*)(ws + o);
    unsigned short* h1b = (unsigned short*)(ws + o);
    o = align(o + (size_t)N_EDGES * 8);
    float* meanbuf = (float*)(ws + o); o = align(o + (size_t)N_NODES * 64 * 4);  // R2
    float* h1      = (float*)(ws + o); o = align(o + (size_t)N_NODES * 64 * 4);

    hipMemsetAsync(bucket_cnt, 0, 256 * sizeof(int), stream);

    bucket_count<<<NBLK_A, 256, 0, stream>>>(dst, bucket_cnt);
    bucket_scan<<<1, 256, 0, stream>>>(bucket_cnt, bucket_base, bucket_cursor);
    bucket_bin<<<NBLK_A, 256, 0, stream>>>(src, dst, bucket_cursor, binned);
    bucket_fine<<<NB, 256, 0, stream>>>(binned, bucket_base, bucket_cnt,
                                        cnt, row_start, csr_src);
    pad_bf16_kernel<<<(N_NODES * 64) / 256, 256, 0, stream>>>(x, xb);

    gather_mean_kernel<<<N_NODES / 16, 256, 0, stream>>>(
        (const unsigned short*)xb, csr_src, row_start, cnt, meanbuf);
    gemm1_kernel<<<(N_NODES + 63) / 64, 256, 0, stream>>>(
        x, meanbuf, W1, b1, h1, h1b);
    gather_mean_kernel<<<N_NODES / 16, 256, 0, stream>>>(
        h1b, csr_src, row_start, cnt, meanbuf);
    gemm23_kernel<<<(N_NODES + 127) / 128, 256, 0, stream>>>(
        h1, meanbuf, W2, b2, W3, b3, out);
}

// Round 7
// 289.261 us; speedup vs baseline: 5.3335x; 5.3335x over previous
//
#include <hip/hip_runtime.h>
#include <hip/hip_bf16.h>

#define N_NODES 100000
#define N_EDGES 1600000
#define IN_CH 50
#define NPB 512                                   // nodes per bucket (dst >> 9)
#define NB ((N_NODES + NPB - 1) / NPB)            // 196 buckets
#define EPB 4096                                  // edges per block, binning passes
#define NBLK_A ((N_EDGES + EPB - 1) / EPB)        // 391 blocks

// ---- 1. coarse bucket histogram ----
__global__ __launch_bounds__(256) void bucket_count(const int* __restrict__ dst,
                                                    int* __restrict__ bucket_cnt) {
    __shared__ int bc[NB];
    int t = threadIdx.x;
    if (t < NB) bc[t] = 0;
    __syncthreads();
    int e0 = blockIdx.x * EPB;
    int e1 = min(e0 + EPB, N_EDGES);
    for (int i = e0 + t; i < e1; i += 256)
        atomicAdd(&bc[dst[i] >> 9], 1);
    __syncthreads();
    if (t < NB) { int v = bc[t]; if (v) atomicAdd(&bucket_cnt[t], v); }
}

// ---- 2. exclusive scan of bucket sizes ----
__global__ __launch_bounds__(256) void bucket_scan(const int* __restrict__ bucket_cnt,
                                                   int* __restrict__ bucket_base,
                                                   int* __restrict__ bucket_cursor) {
    __shared__ int s[256];
    int t = threadIdx.x;
    int v = (t < NB) ? bucket_cnt[t] : 0;
    s[t] = v;
    __syncthreads();
    for (int off = 1; off < 256; off <<= 1) {
        int tmp = (t >= off) ? s[t - off] : 0;
        __syncthreads();
        s[t] += tmp;
        __syncthreads();
    }
    if (t < NB) { int base = s[t] - v; bucket_base[t] = base; bucket_cursor[t] = base; }
}

// ---- 3. bin edges into coarse buckets as packed (dst<<32 | src) ----
__global__ __launch_bounds__(256) void bucket_bin(const int* __restrict__ src,
                                                  const int* __restrict__ dst,
                                                  int* __restrict__ bucket_cursor,
                                                  unsigned long long* __restrict__ binned) {
    __shared__ int bc[NB];
    __shared__ int boff[NB];
    int t = threadIdx.x;
    if (t < NB) bc[t] = 0;
    __syncthreads();
    int e0 = blockIdx.x * EPB;
    int e1 = min(e0 + EPB, N_EDGES);
    for (int i = e0 + t; i < e1; i += 256)
        atomicAdd(&bc[dst[i] >> 9], 1);
    __syncthreads();
    if (t < NB) {
        int v = bc[t];
        boff[t] = v ? atomicAdd(&bucket_cursor[t], v) : 0;
        bc[t] = 0;
    }
    __syncthreads();
    for (int i = e0 + t; i < e1; i += 256) {
        int d = dst[i];
        int b = d >> 9;
        int k = atomicAdd(&bc[b], 1);
        binned[boff[b] + k] =
            ((unsigned long long)(unsigned)d << 32) | (unsigned)src[i];
    }
}

// ---- 4. per-bucket fine sort ----
__global__ __launch_bounds__(256) void bucket_fine(
    const unsigned long long* __restrict__ binned,
    const int* __restrict__ bucket_base, const int* __restrict__ bucket_cnt,
    int* __restrict__ cnt, int* __restrict__ row_start, int* __restrict__ csr_src) {
    __shared__ int lcnt[NPB];
    __shared__ int lofs[NPB];
    __shared__ int sc[256];
    int t = threadIdx.x;
    int b = blockIdx.x;
    int nbase = b * NPB;
    int ebase = bucket_base[b];
    int ecnt  = bucket_cnt[b];
    lcnt[t] = 0; lcnt[t + 256] = 0;
    __syncthreads();
    for (int i = t; i < ecnt; i += 256) {
        int d = (int)(binned[ebase + i] >> 32) - nbase;
        atomicAdd(&lcnt[d], 1);
    }
    __syncthreads();
    int v0 = lcnt[2 * t], v1 = lcnt[2 * t + 1];
    int pair = v0 + v1;
    sc[t] = pair;
    __syncthreads();
    for (int off = 1; off < 256; off <<= 1) {
        int tmp = (t >= off) ? sc[t - off] : 0;
        __syncthreads();
        sc[t] += tmp;
        __syncthreads();
    }
    int excl = sc[t] - pair;
    lofs[2 * t] = excl;
    lofs[2 * t + 1] = excl + v0;
    __syncthreads();
    {
        int n0 = nbase + t;
        if (n0 < N_NODES) { cnt[n0] = lcnt[t]; row_start[n0] = ebase + lofs[t]; }
        int n1 = nbase + t + 256;
        if (n1 < N_NODES) { cnt[n1] = lcnt[t + 256]; row_start[n1] = ebase + lofs[t + 256]; }
    }
    __syncthreads();
    for (int i = t; i < ecnt; i += 256) {
        unsigned long long p = binned[ebase + i];
        int d = (int)(p >> 32) - nbase;
        int k = atomicAdd(&lofs[d], 1);
        csr_src[ebase + k] = (int)(p & 0xffffffffULL);
    }
}

// ---- 5. pad+quantize x [N,50] fp32 -> xb [N,64] bf16 ----
__global__ __launch_bounds__(256) void pad_bf16_kernel(const float* __restrict__ x,
                                                       unsigned short* __restrict__ xb) {
    int t = blockIdx.x * blockDim.x + threadIdx.x;
    int n = t >> 6, c = t & 63;
    float v = (c < IN_CH) ? x[n * IN_CH + c] : 0.0f;
    __hip_bfloat16 hb = __float2bfloat16(v);
    xb[t] = *(unsigned short*)&hb;
}

// unpack 8 bf16 from uint4, predicated fma into acc[0..8)
__device__ __forceinline__ void upadd8(float* a, uint4 v, float p) {
    a[0] = fmaf(p, __uint_as_float(v.x << 16), a[0]);
    a[1] = fmaf(p, __uint_as_float(v.x & 0xffff0000u), a[1]);
    a[2] = fmaf(p, __uint_as_float(v.y << 16), a[2]);
    a[3] = fmaf(p, __uint_as_float(v.y & 0xffff0000u), a[3]);
    a[4] = fmaf(p, __uint_as_float(v.z << 16), a[4]);
    a[5] = fmaf(p, __uint_as_float(v.z & 0xffff0000u), a[5]);
    a[6] = fmaf(p, __uint_as_float(v.w << 16), a[6]);
    a[7] = fmaf(p, __uint_as_float(v.w & 0xffff0000u), a[7]);
}

// wave-local LDS fence: LDS ops of one wave complete in order; no block barrier.
#define WAVE_LDS_FENCE() __asm__ volatile("s_waitcnt lgkmcnt(0)" ::: "memory")

// Gather-mean of 4 nodes (nb..nb+3) per wave, chains interleaved.
// 8 lane-groups of 8; each lane loads 16B (8 bf16 ch) of one edge row.
// On return: acc[i][c] holds the FULL mean (already divided) in ALL lanes,
// for channels cw..cw+7, cw=(lane&7)*8.
__device__ __forceinline__ void gather4(
    const unsigned short* __restrict__ featb, const int* __restrict__ csr_src,
    const int* __restrict__ row_start, const int* __restrict__ cnt,
    int nb, int lane, float acc[4][8]) {
    int g  = lane >> 3;
    int start[4], deg[4], sv[4];
    int dmax = 0;
    #pragma unroll
    for (int i = 0; i < 4; ++i) {
        start[i] = row_start[nb + i];
        deg[i]   = cnt[nb + i];
        dmax = max(dmax, deg[i]);
        #pragma unroll
        for (int c = 0; c < 8; ++c) acc[i][c] = 0.f;
    }
    int cw = (lane & 7) * 8;
    #pragma unroll
    for (int i = 0; i < 4; ++i)
        sv[i] = (lane < deg[i]) ? csr_src[start[i] + lane] : 0;

    #pragma unroll
    for (int cb = 0; cb < 64; cb += 16) {
        if (cb >= dmax) break;                 // wave-uniform
        #pragma unroll
        for (int i = 0; i < 4; ++i) {
            int rem = deg[i] - cb;
            if (rem > 0) {                     // wave-uniform
                int s0 = __shfl(sv[i], cb + g);
                int s1 = __shfl(sv[i], cb + 8 + g);
                float p0 = (g < rem) ? 1.f : 0.f;
                float p1 = (g + 8 < rem) ? 1.f : 0.f;
                uint4 v0 = *(const uint4*)(featb + s0 * 64 + cw);
                uint4 v1 = *(const uint4*)(featb + s1 * 64 + cw);
                upadd8(acc[i], v0, p0);
                upadd8(acc[i], v1, p1);
            }
        }
    }
    if (dmax > 64) {                           // rare tail
        for (int i = 0; i < 4; ++i) {
            for (int c0 = 64; c0 < deg[i]; c0 += 64) {
                int rem = deg[i] - c0; if (rem > 64) rem = 64;
                int sx = (lane < rem) ? csr_src[start[i] + c0 + lane] : 0;
                for (int cb = 0; cb < rem; cb += 16) {
                    int s0 = __shfl(sx, cb + g);
                    int s1 = __shfl(sx, cb + 8 + g);
                    float p0 = (cb + g < rem) ? 1.f : 0.f;
                    float p1 = (cb + 8 + g < rem) ? 1.f : 0.f;
                    uint4 v0 = *(const uint4*)(featb + s0 * 64 + cw);
                    uint4 v1 = *(const uint4*)(featb + s1 * 64 + cw);
                    upadd8(acc[i], v0, p0);
                    upadd8(acc[i], v1, p1);
                }
            }
        }
    }
    #pragma unroll
    for (int i = 0; i < 4; ++i) {
        float inv = 1.0f / fmaxf((float)deg[i], 1.0f);
        #pragma unroll
        for (int c = 0; c < 8; ++c) {
            float t = acc[i][c];
            t += __shfl_xor(t, 8);
            t += __shfl_xor(t, 16);
            t += __shfl_xor(t, 32);
            acc[i][c] = t * inv;
        }
    }
}

// ---- 6. layer 1 fused: 4 nodes/wave; gather(xb) + GEMM(100x64) + ReLU ----
__global__ __launch_bounds__(256) void layer1_fused(
    const float* __restrict__ x, const unsigned short* __restrict__ xb,
    const int* __restrict__ csr_src, const int* __restrict__ row_start,
    const int* __restrict__ cnt, const float* __restrict__ W1,
    const float* __restrict__ b1, float* __restrict__ h1,
    unsigned short* __restrict__ h1b) {
    int wv   = threadIdx.x >> 6;
    int lane = threadIdx.x & 63;
    int nb   = (blockIdx.x * 4 + wv) * 4;      // N_NODES % 16 == 0

    float acc[4][8];
    gather4(xb, csr_src, row_start, cnt, nb, lane, acc);

    __shared__ __align__(16) float selfF[4][4][64];
    __shared__ __align__(16) float meanF[4][4][64];
    #pragma unroll
    for (int i = 0; i < 4; ++i) {
        if (lane < IN_CH) selfF[wv][i][lane] = x[(nb + i) * IN_CH + lane];
        if (lane < 8) {
            *(float4*)&meanF[wv][i][lane * 8] =
                make_float4(acc[i][0], acc[i][1], acc[i][2], acc[i][3]);
            *(float4*)&meanF[wv][i][lane * 8 + 4] =
                make_float4(acc[i][4], acc[i][5], acc[i][6], acc[i][7]);
        }
    }
    WAVE_LDS_FENCE();

    float ao[4];
    float bb = b1[lane];
    #pragma unroll
    for (int i = 0; i < 4; ++i) ao[i] = bb;
    #pragma unroll
    for (int k = 0; k < IN_CH; ++k) {
        float w = W1[k * 64 + lane];           // loaded once, reused x4
        #pragma unroll
        for (int i = 0; i < 4; ++i) ao[i] = fmaf(selfF[wv][i][k], w, ao[i]);
    }
    #pragma unroll
    for (int k = 0; k < IN_CH; ++k) {
        float w = W1[(IN_CH + k) * 64 + lane];
        #pragma unroll
        for (int i = 0; i < 4; ++i) ao[i] = fmaf(meanF[wv][i][k], w, ao[i]);
    }
    #pragma unroll
    for (int i = 0; i < 4; ++i) {
        float r = fmaxf(ao[i], 0.f);
        h1[((nb + i) << 6) + lane] = r;
        __hip_bfloat16 hb = __float2bfloat16(r);
        h1b[((nb + i) << 6) + lane] = *(unsigned short*)&hb;
    }
}

// ---- 7. layers 2+3 fused: 4 nodes/wave; gather(h1b) + GEMM(128x32) + ReLU + dot(W3) ----
__global__ __launch_bounds__(256) void layer23_fused(
    const float* __restrict__ h1, const unsigned short* __restrict__ h1b,
    const int* __restrict__ csr_src, const int* __restrict__ row_start,
    const int* __restrict__ cnt, const float* __restrict__ W2,
    const float* __restrict__ b2, const float* __restrict__ W3,
    const float* __restrict__ b3, float* __restrict__ out) {
    int wv   = threadIdx.x >> 6;
    int lane = threadIdx.x & 63;
    int nb   = (blockIdx.x * 4 + wv) * 4;

    float acc[4][8];
    gather4(h1b, csr_src, row_start, cnt, nb, lane, acc);

    __shared__ __align__(16) float featL[4][4][128];   // [0,64)=self, [64,128)=mean
    #pragma unroll
    for (int i = 0; i < 4; ++i) {
        featL[wv][i][lane] = h1[((nb + i) << 6) + lane];
        if (lane < 8) {
            *(float4*)&featL[wv][i][64 + lane * 8] =
                make_float4(acc[i][0], acc[i][1], acc[i][2], acc[i][3]);
            *(float4*)&featL[wv][i][64 + lane * 8 + 4] =
                make_float4(acc[i][4], acc[i][5], acc[i][6], acc[i][7]);
        }
    }
    WAVE_LDS_FENCE();

    int hh = lane >> 5;                        // half-wave id: nodes nb+hh, nb+2+hh
    int j  = lane & 31;
    float a0 = b2[j], a1 = a0;
    #pragma unroll
    for (int k = 0; k < 128; ++k) {
        float w = W2[k * 32 + j];
        a0 = fmaf(featL[wv][hh][k],     w, a0);
        a1 = fmaf(featL[wv][2 + hh][k], w, a1);
    }
    float w3 = W3[j];
    float c3 = b3[0];
    float v0 = fmaxf(a0, 0.f) * w3;
    float v1 = fmaxf(a1, 0.f) * w3;
    #pragma unroll
    for (int off = 1; off <= 16; off <<= 1) {
        v0 += __shfl_xor(v0, off);
        v1 += __shfl_xor(v1, off);
    }
    if (j == 0) {
        out[nb + hh]     = v0 + c3;
        out[nb + 2 + hh] = v1 + c3;
    }
}

extern "C" void kernel_launch(void* const* d_in, const int* in_sizes, int n_in,
                              void* d_out, int out_size, void* d_ws, size_t ws_size,
                              hipStream_t stream) {
    const float* x   = (const float*)d_in[0];
    const int*   ei  = (const int*)d_in[1];
    const int*   src = ei;
    const int*   dst = ei + N_EDGES;
    const float* W1  = (const float*)d_in[2];
    const float* b1  = (const float*)d_in[3];
    const float* W2  = (const float*)d_in[4];
    const float* b2  = (const float*)d_in[5];
    const float* W3  = (const float*)d_in[6];
    const float* b3  = (const float*)d_in[7];
    float* out = (float*)d_out;

    // ws (~58 MB): buckets | cnt | row_start | csr_src |
    //   R1 12.8MB: binned u64[E] ALIAS xb bf16[N*64] (binned dead before pad) |
    //   h1b bf16[N*64] 12.8MB | h1 f32[N*64] 25.6MB
    char* ws = (char*)d_ws;
    auto align = [](size_t v) { return (v + 255) & ~(size_t)255; };
    size_t o = 0;
    int* bucket_cnt    = (int*)(ws + o); o = align(o + 256 * 4);
    int* bucket_base   = (int*)(ws + o); o = align(o + 256 * 4);
    int* bucket_cursor = (int*)(ws + o); o = align(o + 256 * 4);
    int* cnt       = (int*)(ws + o); o = align(o + (size_t)N_NODES * 4);
    int* row_start = (int*)(ws + o); o = align(o + (size_t)N_NODES * 4);
    int* csr_src   = (int*)(ws + o); o = align(o + (size_t)N_EDGES * 4);
    unsigned long long* binned = (unsigned long long*)(ws + o);   // 12.8 MB
    unsigned short* xb = (unsigned short*)(ws + o);               // alias
    o = align(o + (size_t)N_EDGES * 8);
    unsigned short* h1b = (unsigned short*)(ws + o); o = align(o + (size_t)N_NODES * 64 * 2);
    float* h1 = (float*)(ws + o); o = align(o + (size_t)N_NODES * 64 * 4);

    hipMemsetAsync(bucket_cnt, 0, 256 * sizeof(int), stream);

    bucket_count<<<NBLK_A, 256, 0, stream>>>(dst, bucket_cnt);
    bucket_scan<<<1, 256, 0, stream>>>(bucket_cnt, bucket_base, bucket_cursor);
    bucket_bin<<<NBLK_A, 256, 0, stream>>>(src, dst, bucket_cursor, binned);
    bucket_fine<<<NB, 256, 0, stream>>>(binned, bucket_base, bucket_cnt,
                                        cnt, row_start, csr_src);
    pad_bf16_kernel<<<(N_NODES * 64) / 256, 256, 0, stream>>>(x, xb);

    layer1_fused<<<N_NODES / 16, 256, 0, stream>>>(x, xb, csr_src, row_start, cnt,
                                                   W1, b1, h1, h1b);
    layer23_fused<<<N_NODES / 16, 256, 0, stream>>>(h1, h1b, csr_src, row_start, cnt,
                                                    W2, b2, W3, b3, out);
}